// Round 8
// baseline (780.362 us; speedup 1.0000x reference)
//
#include <hip/hip_runtime.h>

// 400-step diffusion stencil; temporal blocking, 16 steps/launch, 25 launches.
// u_{t+1} = mask * (u_t + 0.225 * lap5(u_t) + dt * a), zero Dirichlet mask.
//
// Round-8 change (single variable vs round 7, which ran 760 us total,
// ~30 us/dispatch): replace __shfl_up/__shfl_down (ds_bpermute, shares the
// LDS pipe: 128 ops/CU/substep = half the DS-pipe cost) with DPP wave
// shifts on the VALU pipe:
//   wave_shr:1 (0x138): lane n <- lane n-1  == shfl_up(x,1)
//   wave_shl:1 (0x130): lane n <- lane n+1  == shfl_down(x,1)
// (CDNA keeps gfx9 wave DPP; direction per AMD wave-scan idiom: row_shr:N
// pulls from lane n-N.) OOB lanes read 0 (bound_ctrl) -- garbage lands on
// ring-0 tile columns only, covered by the existing staleness invariant.
//
// Design (validated rounds 6-7): state in registers; thread (cq,gs) owns
// rows rbeg..rbeg+3 x cols 4cq..4cq+3 for all 16 substeps. LDS only for
// strip-boundary halo rows, double-buffered -> 1 barrier/substep, all
// accesses ds_*_b128 conflict-free. IN=128, BB=96, 1024 thr, grid 16x16 =
// 256 blocks = exactly 1 block/CU.
// Validity: ring->=s exact after s substeps; core rows/cols 16..111 exact.

#define HH 1501
#define NUM_T 400
#define TSTEPS 16
#define BB 96
#define IN 128           // BB + 2*TSTEPS
#define NTH 1024         // 32 col-quads x 32 row-groups
#define DT 1e-7f
#define SP 0.225f

__device__ __forceinline__ float dpp_shr1(float x) {   // lane n <- lane n-1
    return __int_as_float(__builtin_amdgcn_update_dpp(
        0, __float_as_int(x), 0x138, 0xF, 0xF, true));
}
__device__ __forceinline__ float dpp_shl1(float x) {   // lane n <- lane n+1
    return __int_as_float(__builtin_amdgcn_update_dpp(
        0, __float_as_int(x), 0x130, 0xF, 0xF, true));
}

__global__ __launch_bounds__(NTH) void furnace_tb(
    const float* __restrict__ uin,
    const float* __restrict__ a,
    float* __restrict__ uout)
{
    // halo rows, double-buffered. h_top[b][g] = group g's row rbeg (slot 32
    // only read, never written -> garbage, feeds ring-0 row only).
    // h_bot[b][g+1] = group g's row rbeg+3; h_bot[b][0] = staged tile row 0.
    __shared__ __align__(16) float h_top[2][33][IN];
    __shared__ __align__(16) float h_bot[2][33][IN];

    const int tid = threadIdx.x;
    const int cq  = tid & 31;        // column quad 0..31 (cols 4cq..4cq+3)
    const int gs  = tid >> 5;        // row group 0..31 (rows rbeg..rbeg+3)
    const int ox  = blockIdx.x * BB;
    const int oy  = blockIdx.y * BB;
    const int c0  = 4 * cq;
    const int gx0 = ox - TSTEPS + c0;
    const int rbeg = 1 + 4 * gs;     // 1..125

    float4 u[4], fr[4], mk[4];

    // ---- stage strip + forcing + mask into registers ----
    #pragma unroll
    for (int j = 0; j < 4; ++j) {
        const int rr = rbeg + j;
        const int gy = oy - TSTEPS + rr;
        const bool rowin = (gy >= 0 && gy < HH);
        const float rowm = (gy <= 0 || gy >= HH - 1) ? 0.0f : 1.0f;
        float tu[4], tf[4], tm[4];
        #pragma unroll
        for (int k = 0; k < 4; ++k) {
            const int gx = gx0 + k;
            const bool inb = rowin && (gx >= 0 && gx < HH);
            tu[k] = inb ? uin[gy * HH + gx] : 0.0f;
            tf[k] = inb ? DT * a[gy * HH + gx] : 0.0f;
            tm[k] = (gx <= 0 || gx >= HH - 1) ? 0.0f : rowm;
        }
        u[j]  = make_float4(tu[0], tu[1], tu[2], tu[3]);
        fr[j] = make_float4(tf[0], tf[1], tf[2], tf[3]);
        mk[j] = make_float4(tm[0], tm[1], tm[2], tm[3]);
    }

    // prefill h_bot[*][0] with tile row 0 (group 0's "up"); stale after
    // substep 0, which is safe (ring-0 row).
    if (gs == 0) {
        const int gy = oy - TSTEPS;
        float t[4];
        #pragma unroll
        for (int k = 0; k < 4; ++k) {
            const int gx = gx0 + k;
            t[k] = (gy >= 0 && gy < HH && gx >= 0 && gx < HH)
                 ? uin[gy * HH + gx] : 0.0f;
        }
        const float4 r0 = make_float4(t[0], t[1], t[2], t[3]);
        *(float4*)&h_bot[0][0][c0] = r0;
        *(float4*)&h_bot[1][0][c0] = r0;
    }

    // ---- 16 substeps, one barrier each ----
    #pragma unroll 1
    for (int s = 0; s < TSTEPS; ++s) {
        const int b = s & 1;
        *(float4*)&h_top[b][gs][c0]     = u[0];   // my top row (old)
        *(float4*)&h_bot[b][gs + 1][c0] = u[3];   // my bottom row (old)
        __syncthreads();
        float4 pold = *(const float4*)&h_bot[b][gs][c0];      // row rbeg-1
        const float4 dne = *(const float4*)&h_top[b][gs + 1][c0]; // row rbeg+4
        #pragma unroll
        for (int j = 0; j < 4; ++j) {
            const float4 cur = u[j];
            const float4 dnv = (j < 3) ? u[j + 1] : dne;
            const float lf = dpp_shr1(cur.w);    // col c0-1 (old), lane n-1
            const float rt = dpp_shl1(cur.x);    // col c0+4 (old), lane n+1
            float4 nv;
            nv.x = (cur.x + SP * ((lf    + cur.y) + (pold.x + dnv.x) - 4.0f * cur.x) + fr[j].x) * mk[j].x;
            nv.y = (cur.y + SP * ((cur.x + cur.z) + (pold.y + dnv.y) - 4.0f * cur.y) + fr[j].y) * mk[j].y;
            nv.z = (cur.z + SP * ((cur.y + cur.w) + (pold.z + dnv.z) - 4.0f * cur.z) + fr[j].z) * mk[j].z;
            nv.w = (cur.w + SP * ((cur.z + rt   ) + (pold.w + dnv.w) - 4.0f * cur.w) + fr[j].w) * mk[j].w;
            u[j] = nv;
            pold = cur;
        }
        // no second barrier: next substep writes the OTHER halo buffer, and
        // the barrier above orders buffer reuse two substeps apart.
    }

    // ---- write 96x96 core (tile rows/cols 16..111) from registers ----
    if (cq >= 4 && cq <= 27) {
        #pragma unroll
        for (int j = 0; j < 4; ++j) {
            const int rr = rbeg + j;
            if (rr >= TSTEPS && rr < TSTEPS + BB) {
                const int gy = oy + (rr - TSTEPS);
                if (gy < HH) {
                    const float v[4] = { u[j].x, u[j].y, u[j].z, u[j].w };
                    #pragma unroll
                    for (int k = 0; k < 4; ++k) {
                        const int gx = gx0 + k;
                        if (gx < HH) uout[gy * HH + gx] = v[k];
                    }
                }
            }
        }
    }
}

extern "C" void kernel_launch(void* const* d_in, const int* in_sizes, int n_in,
                              void* d_out, int out_size, void* d_ws, size_t ws_size,
                              hipStream_t stream)
{
    const float* u0 = (const float*)d_in[0];
    const float* a  = (const float*)d_in[1];
    float* out = (float*)d_out;
    float* ws  = (float*)d_ws;   // one H*H fp32 buffer (9.01 MB)

    dim3 block(NTH, 1, 1);
    dim3 grid((HH + BB - 1) / BB, (HH + BB - 1) / BB, 1);  // 16 x 16 = 256

    const int nLaunch = NUM_T / TSTEPS;  // 25
    const float* src = u0;
    for (int k = 0; k < nLaunch; ++k) {
        float* dst = (k & 1) ? ws : out;   // k even -> d_out; k=24 -> d_out
        furnace_tb<<<grid, block, 0, stream>>>(src, a, dst);
        src = dst;
    }
}